// Round 1
// baseline (1095.202 us; speedup 1.0000x reference)
//
#include <hip/hip_runtime.h>

typedef _Float16 f16;
typedef __attribute__((ext_vector_type(8))) _Float16 f16x8;
typedef __attribute__((ext_vector_type(4))) float f32x4v;

#define DEVI __device__ __forceinline__

DEVI unsigned short f2h_bits(float x) {
    _Float16 h = (_Float16)x;
    return __builtin_bit_cast(unsigned short, h);
}
DEVI unsigned pack2(float a, float b) {
    return (unsigned)f2h_bits(a) | ((unsigned)f2h_bits(b) << 16);
}

// Stage a 128-row x 64-f16-col tile (row stride = ld elements) into linear LDS
// via global_load_lds(16B), with XOR-swizzled SOURCE chunks (rule 21): LDS chunk
// (row, c) receives global chunk (row, c ^ (row&7)). Reads then XOR the same way.
DEVI void stage128(f16* lds, const f16* g, int ld, int w, int lane) {
#pragma unroll
    for (int j = 0; j < 4; ++j) {
        int q   = j * 256 + w * 64 + lane;
        int row = q >> 3;
        int c   = q & 7;
        int cs  = c ^ (row & 7);
        const f16* src = g + (size_t)row * ld + cs * 8;
        f16* dst = lds + q * 8; // byte offset q*16
        __builtin_amdgcn_global_load_lds((const __attribute__((address_space(1))) void*)src,
                                         (__attribute__((address_space(3))) void*)dst, 16, 0, 0);
    }
}

// Read an MFMA A/B fragment (8 f16) from a swizzled tile: element (row,k) lives at
// byte row*128 + ((2k) ^ ((row&7)<<4)).
DEVI f16x8 read_frag(const f16* lds, int row, int kbyte) {
    int off = row * 128 + (kbyte ^ ((row & 7) << 4));
    return *(const f16x8*)((const char*)lds + off);
}

#define MFMA(a, b, c) __builtin_amdgcn_mfma_f32_16x16x32_f16(a, b, c, 0, 0, 0)

// ---------------------------------------------------------------------------
// C[M,N] = A[M,K] * B[N,K]^T (+bias), f16 inputs, f32 accumulate.
// 128x128 tile, 4 waves, BK=64. outMode: 1 = write f32 Cf, 2 = write f16 Ch.
// ---------------------------------------------------------------------------
__global__ __launch_bounds__(256) void gemm_bt(
    const f16* __restrict__ A, const f16* __restrict__ B,
    const float* __restrict__ bias,
    float* __restrict__ Cf, f16* __restrict__ Ch,
    int K, int lda, int ldb, int ldc,
    long batchA, long batchB, long batchC,
    int outMode)
{
    __shared__ f16 As[128 * 64];
    __shared__ f16 Bs[128 * 64];
    const int z = blockIdx.z;
    const f16* Ab = A + (size_t)z * batchA + (size_t)blockIdx.y * 128 * lda;
    const f16* Bb = B + (size_t)z * batchB + (size_t)blockIdx.x * 128 * ldb;
    const int t = threadIdx.x, w = t >> 6, lane = t & 63;
    const int r = lane & 15, h = lane >> 4;
    const int wr = w >> 1, wc = w & 1;
    f32x4v acc[4][4] = {};

#pragma unroll 1
    for (int k0 = 0; k0 < K; k0 += 64) {
        stage128(As, Ab + k0, lda, w, lane);
        stage128(Bs, Bb + k0, ldb, w, lane);
        __syncthreads();
#pragma unroll
        for (int kk = 0; kk < 2; ++kk) {
            const int kb = kk * 64 + h * 16;
            f16x8 a[4], b[4];
#pragma unroll
            for (int mi = 0; mi < 4; ++mi) a[mi] = read_frag(As, wr * 64 + mi * 16 + r, kb);
#pragma unroll
            for (int ni = 0; ni < 4; ++ni) b[ni] = read_frag(Bs, wc * 64 + ni * 16 + r, kb);
#pragma unroll
            for (int mi = 0; mi < 4; ++mi)
#pragma unroll
                for (int ni = 0; ni < 4; ++ni)
                    acc[mi][ni] = MFMA(a[mi], b[ni], acc[mi][ni]);
        }
        __syncthreads();
    }

    const int m0 = blockIdx.y * 128 + wr * 64;
    const int n0 = blockIdx.x * 128 + wc * 64;
#pragma unroll
    for (int ni = 0; ni < 4; ++ni) {
        const int col = n0 + ni * 16 + r;
        const float bv = bias ? bias[col] : 0.f;
#pragma unroll
        for (int mi = 0; mi < 4; ++mi) {
#pragma unroll
            for (int tt = 0; tt < 4; ++tt) {
                const int row = m0 + mi * 16 + h * 4 + tt;
                const float v = acc[mi][ni][tt] + bv;
                if (outMode & 1) Cf[(size_t)z * batchC + (size_t)row * ldc + col] = v;
                if (outMode & 2) Ch[(size_t)z * batchC + (size_t)row * ldc + col] = (f16)v;
            }
        }
    }
}

// ---------------------------------------------------------------------------
// f32 [B,L,D] -> f16 plain [B,L,D] and f16 transposed [B,D,L]. 64x64 tiles.
// ---------------------------------------------------------------------------
__global__ __launch_bounds__(256) void transpose_cast(
    const float* __restrict__ in, f16* __restrict__ plain, f16* __restrict__ tr)
{
    __shared__ unsigned short tile[64][72];
    const int z = blockIdx.z, l0 = blockIdx.y * 64, d0 = blockIdx.x * 64;
    const int t = threadIdx.x, r = t >> 4, c4 = (t & 15) * 4;
#pragma unroll
    for (int rep = 0; rep < 4; ++rep) {
        const int l = rep * 16 + r;
        const size_t gi = ((size_t)z * 2048 + l0 + l) * 1024 + d0 + c4;
        const f32x4v v = *(const f32x4v*)&in[gi];
        ushort4 u = make_ushort4(f2h_bits(v[0]), f2h_bits(v[1]), f2h_bits(v[2]), f2h_bits(v[3]));
        *(ushort4*)&plain[gi] = u;
        tile[c4 + 0][l] = u.x;
        tile[c4 + 1][l] = u.y;
        tile[c4 + 2][l] = u.z;
        tile[c4 + 3][l] = u.w;
    }
    __syncthreads();
#pragma unroll
    for (int rep = 0; rep < 4; ++rep) {
        const int d = rep * 16 + r;
        ushort4 u = make_ushort4(tile[d][c4 + 0], tile[d][c4 + 1], tile[d][c4 + 2], tile[d][c4 + 3]);
        *(ushort4*)&tr[((size_t)z * 1024 + d0 + d) * 2048 + l0 + c4] = u;
    }
}

__global__ void cast_w(const float* __restrict__ in, f16* __restrict__ out) {
    const int i = (blockIdx.x * 256 + threadIdx.x) * 4;
    f32x4v v = *(const f32x4v*)&in[i];
    *(ushort4*)&out[i] = make_ushort4(f2h_bits(v[0]), f2h_bits(v[1]), f2h_bits(v[2]), f2h_bits(v[3]));
}

// Wcat[o][0:1024] = Wab[o][:], Wcat[o][1024:2048] = Wba[o][:]
__global__ void cast_cat(const float* __restrict__ wab, const float* __restrict__ wba,
                         f16* __restrict__ out) {
    const int i = (blockIdx.x * 256 + threadIdx.x) * 4;
    const int row = i >> 10, col = i & 1023;
    f32x4v va = *(const f32x4v*)&wab[i];
    f32x4v vb = *(const f32x4v*)&wba[i];
    *(ushort4*)&out[(size_t)row * 2048 + col] =
        make_ushort4(f2h_bits(va[0]), f2h_bits(va[1]), f2h_bits(va[2]), f2h_bits(va[3]));
    *(ushort4*)&out[(size_t)row * 2048 + 1024 + col] =
        make_ushort4(f2h_bits(vb[0]), f2h_bits(vb[1]), f2h_bits(vb[2]), f2h_bits(vb[3]));
}

// ---------------------------------------------------------------------------
// Row softmax stats: one block per row (16384 rows of 2048 f32).
// ---------------------------------------------------------------------------
__global__ __launch_bounds__(256) void row_stats(const float* __restrict__ S,
                                                 float* __restrict__ rmax,
                                                 float* __restrict__ rsumInv)
{
    const size_t row = blockIdx.x;
    const float* p = S + row * 2048;
    const int t = threadIdx.x, wid = t >> 6, lane = t & 63;
    const f32x4v v0 = *(const f32x4v*)&p[t * 4];
    const f32x4v v1 = *(const f32x4v*)&p[1024 + t * 4];
    float m = fmaxf(fmaxf(fmaxf(v0[0], v0[1]), fmaxf(v0[2], v0[3])),
                    fmaxf(fmaxf(v1[0], v1[1]), fmaxf(v1[2], v1[3])));
    for (int off = 32; off; off >>= 1) m = fmaxf(m, __shfl_xor(m, off));
    __shared__ float red[8];
    if (lane == 0) red[wid] = m;
    __syncthreads();
    m = fmaxf(fmaxf(red[0], red[1]), fmaxf(red[2], red[3]));
    float s = 0.f;
#pragma unroll
    for (int j = 0; j < 4; ++j) { s += __expf(v0[j] - m); s += __expf(v1[j] - m); }
    for (int off = 32; off; off >>= 1) s += __shfl_xor(s, off);
    if (lane == 0) red[4 + wid] = s;
    __syncthreads();
    if (t == 0) {
        rmax[row] = m;
        rsumInv[row] = 1.f / (red[4] + red[5] + red[6] + red[7]);
    }
}

// Column stats: partial (max, sumexp) over 64-row chunks, then combine.
__global__ __launch_bounds__(256) void col_part(const float* __restrict__ S,
                                                float* __restrict__ pmax,
                                                float* __restrict__ psum)
{
    const int z = blockIdx.z, lc = blockIdx.y;
    const int col = blockIdx.x * 256 + threadIdx.x;
    const float* p = S + (size_t)z * 2048 * 2048 + (size_t)lc * 64 * 2048 + col;
    float m = -1e30f;
#pragma unroll 8
    for (int l = 0; l < 64; ++l) m = fmaxf(m, p[(size_t)l * 2048]);
    float s = 0.f;
#pragma unroll 8
    for (int l = 0; l < 64; ++l) s += __expf(p[(size_t)l * 2048] - m);
    const size_t o = ((size_t)z * 32 + lc) * 2048 + col;
    pmax[o] = m;
    psum[o] = s;
}

__global__ void col_fin(const float* __restrict__ pmax, const float* __restrict__ psum,
                        float* __restrict__ cmax, float* __restrict__ csumInv)
{
    const int g = blockIdx.x * 256 + threadIdx.x; // 0..16383
    const int z = g >> 11, col = g & 2047;
    const float* pm = pmax + (size_t)z * 32 * 2048 + col;
    const float* ps = psum + (size_t)z * 32 * 2048 + col;
    float m = -1e30f;
#pragma unroll
    for (int i = 0; i < 32; ++i) m = fmaxf(m, pm[(size_t)i * 2048]);
    float s = 0.f;
#pragma unroll
    for (int i = 0; i < 32; ++i) s += ps[(size_t)i * 2048] * __expf(pm[(size_t)i * 2048] - m);
    cmax[g] = m;
    csumInv[g] = 1.f / s;
}

// ---------------------------------------------------------------------------
// Dual attention GEMM. Per block: m-tile 64 (L dim), d-tile 128 (D dim), one batch.
// Loop l in 64-chunks: read S[l..][m-tile] once, build both exp-weight tiles
// (Pa: col-softmax numerators for output_a; Pb: row-softmax * rsumInv for output_b)
// into swizzled LDS, MFMA against transposed input tiles Xa/Xb.
//   output_a[m,d] = csumInv[m] * sum_l exp(S[l,m]-cmax[m]) * input_b[l,d]
//   output_b[m,d] =              sum_l exp(S[l,m]-rmax[l])*rsumInv[l] * input_a[l,d]
// Writes f32 into d_out and f16 into cat[:, 0:1024]=out_a, [:,1024:2048]=out_b.
// ---------------------------------------------------------------------------
__global__ __launch_bounds__(256) void attn_dual(
    const float* __restrict__ S, const f16* __restrict__ aT, const f16* __restrict__ bT,
    const float* __restrict__ rmax, const float* __restrict__ rsumInv,
    const float* __restrict__ cmax, const float* __restrict__ csumInv,
    float* __restrict__ outA, float* __restrict__ outB, f16* __restrict__ cat)
{
    __shared__ f16 Pa[64 * 64], Pb[64 * 64], Xa[128 * 64], Xb[128 * 64];
    const int z = blockIdx.z, m0 = blockIdx.y * 64, d0 = blockIdx.x * 128;
    const float* Sb = S + (size_t)z * 2048 * 2048;
    const f16* aTb = aT + (size_t)z * 1024 * 2048 + (size_t)d0 * 2048;
    const f16* bTb = bT + (size_t)z * 1024 * 2048 + (size_t)d0 * 2048;
    const int t = threadIdx.x, w = t >> 6, lane = t & 63;
    const int sr = t >> 4, sc4 = (t & 15) * 4;
    const f32x4v cm4 = *(const f32x4v*)&cmax[(size_t)z * 2048 + m0 + sc4];
    f32x4v accA[4][2] = {}, accB[4][2] = {};

#pragma unroll 1
    for (int l0 = 0; l0 < 2048; l0 += 64) {
        // issue async X staging first so it overlaps the exp work
        stage128(Xa, aTb + l0, 2048, w, lane);
        stage128(Xb, bTb + l0, 2048, w, lane);
#pragma unroll
        for (int rep = 0; rep < 2; ++rep) {
            const int p = rep * 16 + sr;      // l-pair index 0..31
            const int l = l0 + p * 2;
            const f32x4v s0 = *(const f32x4v*)&Sb[(size_t)l * 2048 + m0 + sc4];
            const f32x4v s1 = *(const f32x4v*)&Sb[(size_t)(l + 1) * 2048 + m0 + sc4];
            const float rm0 = rmax[(size_t)z * 2048 + l];
            const float ri0 = rsumInv[(size_t)z * 2048 + l];
            const float rm1 = rmax[(size_t)z * 2048 + l + 1];
            const float ri1 = rsumInv[(size_t)z * 2048 + l + 1];
#pragma unroll
            for (int j = 0; j < 4; ++j) {
                const int m = sc4 + j;
                const int off = m * 128 + ((p * 4) ^ ((m & 7) << 4)); // byte of element l within row m
                const float pa0 = __expf(s0[j] - cm4[j]);
                const float pa1 = __expf(s1[j] - cm4[j]);
                const float pb0 = __expf(s0[j] - rm0) * ri0;
                const float pb1 = __expf(s1[j] - rm1) * ri1;
                *(unsigned*)((char*)Pa + off) = pack2(pa0, pa1);
                *(unsigned*)((char*)Pb + off) = pack2(pb0, pb1);
            }
        }
        __syncthreads();
        const int r = lane & 15, h = lane >> 4;
#pragma unroll
        for (int kk = 0; kk < 2; ++kk) {
            const int kb = kk * 64 + h * 16;
            f16x8 pa[4], pb[4], xa[2], xb[2];
#pragma unroll
            for (int mi = 0; mi < 4; ++mi) {
                pa[mi] = read_frag(Pa, mi * 16 + r, kb);
                pb[mi] = read_frag(Pb, mi * 16 + r, kb);
            }
#pragma unroll
            for (int di = 0; di < 2; ++di) {
                xa[di] = read_frag(Xa, w * 32 + di * 16 + r, kb);
                xb[di] = read_frag(Xb, w * 32 + di * 16 + r, kb);
            }
#pragma unroll
            for (int mi = 0; mi < 4; ++mi)
#pragma unroll
                for (int di = 0; di < 2; ++di) {
                    accA[mi][di] = MFMA(pa[mi], xb[di], accA[mi][di]);
                    accB[mi][di] = MFMA(pb[mi], xa[di], accB[mi][di]);
                }
        }
        __syncthreads();
    }

    const int r = lane & 15, h = lane >> 4;
#pragma unroll
    for (int mi = 0; mi < 4; ++mi) {
#pragma unroll
        for (int tt = 0; tt < 4; ++tt) {
            const int m = m0 + mi * 16 + h * 4 + tt;
            const size_t rowg = (size_t)z * 2048 + m;
            const float ci = csumInv[rowg];
#pragma unroll
            for (int di = 0; di < 2; ++di) {
                const int d = d0 + w * 32 + di * 16 + r;
                const float va = accA[mi][di][tt] * ci;
                const float vb = accB[mi][di][tt];
                outA[rowg * 1024 + d] = va;
                outB[rowg * 1024 + d] = vb;
                cat[rowg * 2048 + d] = (f16)va;
                cat[rowg * 2048 + 1024 + d] = (f16)vb;
            }
        }
    }
}

// ---------------------------------------------------------------------------
extern "C" void kernel_launch(void* const* d_in, const int* in_sizes, int n_in,
                              void* d_out, int out_size, void* d_ws, size_t ws_size,
                              hipStream_t stream) {
    const float* in_a = (const float*)d_in[0];
    const float* in_b = (const float*)d_in[1];
    const float* Wa   = (const float*)d_in[2];
    const float* ba   = (const float*)d_in[3];
    const float* Wb   = (const float*)d_in[4];
    const float* bb   = (const float*)d_in[5];
    const float* Wab  = (const float*)d_in[6];
    const float* bab  = (const float*)d_in[7];
    const float* Wba  = (const float*)d_in[8];

    char* ws = (char*)d_ws;
    // Workspace layout with liveness-based overlays (~268 MB total):
    f16*   aT      = (f16*)(ws + 0);          // [8,1024,2048]  33,554,432 B  (live -> attn)
    f16*   bT      = (f16*)(ws + 33554432);   //                33,554,432 B
    f16*   aB      = (f16*)(ws + 67108864);   // [8,2048,1024]  33,554,432 B  (live -> K1)
    f16*   bB      = (f16*)(ws + 100663296);  //                33,554,432 B
    float* S       = (float*)(ws + 67108864); // [8,2048,2048] 134,217,728 B  (overlays aB/bB; written after K1)
    f16*   maH     = (f16*)(ws + 201326592);  // mapped_a f16   33,554,432 B  (live -> K2)
    f16*   mbH     = (f16*)(ws + 234881024);
    f16*   catH    = (f16*)(ws + 201326592);  // [16384,2048] f16, overlays maH/mbH (written in attn, after K2)
    f16*   WaH     = (f16*)(ws + 268435456);  // 2,097,152 B
    f16*   WbH     = (f16*)(ws + 270532608);
    f16*   WcatH   = (f16*)(ws + 272629760);  // [1024,2048]   4,194,304 B
    float* rmaxP   = (float*)(ws + 276824064);
    float* rsumIP  = (float*)(ws + 276889600);
    float* cmaxP   = (float*)(ws + 276955136);
    float* csumIP  = (float*)(ws + 277020672);
    float* pmaxP   = (float*)(ws + 277086208); // [8,32,2048]   2,097,152 B
    float* psumP   = (float*)(ws + 279183360); //               2,097,152 B

    float* outA  = (float*)d_out;
    float* outB  = outA + 16777216;
    float* outAB = outB + 16777216;

    dim3 blk(256);

    transpose_cast<<<dim3(16, 32, 8), blk, 0, stream>>>(in_a, aB, aT);
    transpose_cast<<<dim3(16, 32, 8), blk, 0, stream>>>(in_b, bB, bT);
    cast_w<<<dim3(1024), blk, 0, stream>>>(Wa, WaH);
    cast_w<<<dim3(1024), blk, 0, stream>>>(Wb, WbH);
    cast_cat<<<dim3(1024), blk, 0, stream>>>(Wab, Wba, WcatH);

    // mapped_a = in_a @ Wa^T + ba  (f16 out), mapped_b likewise
    gemm_bt<<<dim3(8, 128, 1), blk, 0, stream>>>(aB, WaH, ba, nullptr, maH,
                                                 1024, 1024, 1024, 1024, 0, 0, 0, 2);
    gemm_bt<<<dim3(8, 128, 1), blk, 0, stream>>>(bB, WbH, bb, nullptr, mbH,
                                                 1024, 1024, 1024, 1024, 0, 0, 0, 2);
    // scores[b] = mapped_a[b] @ mapped_b[b]^T  (f32 out)
    gemm_bt<<<dim3(16, 16, 8), blk, 0, stream>>>(maH, mbH, nullptr, S, nullptr,
                                                 1024, 1024, 1024, 2048,
                                                 2048L * 1024L, 2048L * 1024L, 2048L * 2048L, 1);

    row_stats<<<dim3(16384), blk, 0, stream>>>(S, rmaxP, rsumIP);
    col_part<<<dim3(8, 32, 8), blk, 0, stream>>>(S, pmaxP, psumP);
    col_fin<<<dim3(64), blk, 0, stream>>>(pmaxP, psumP, cmaxP, csumIP);

    attn_dual<<<dim3(8, 32, 8), blk, 0, stream>>>(S, aT, bT, rmaxP, rsumIP, cmaxP, csumIP,
                                                  outA, outB, catH);

    // output_ab = cat @ Wcat^T + bab  (f32 out)
    gemm_bt<<<dim3(8, 128, 1), blk, 0, stream>>>(catH, WcatH, bab, outAB, nullptr,
                                                 2048, 2048, 2048, 1024, 0, 0, 0, 1);

    (void)in_sizes; (void)n_in; (void)out_size; (void)ws_size;
}

// Round 2
// 1021.500 us; speedup vs baseline: 1.0722x; 1.0722x over previous
//
#include <hip/hip_runtime.h>

typedef _Float16 f16;
typedef __attribute__((ext_vector_type(8))) _Float16 f16x8;
typedef __attribute__((ext_vector_type(4))) float f32x4v;

#define DEVI __device__ __forceinline__

DEVI unsigned short f2h_bits(float x) {
    _Float16 h = (_Float16)x;
    return __builtin_bit_cast(unsigned short, h);
}

// Stage a 128-row x 64-f16-col tile (row stride = ld elements) into linear LDS
// via global_load_lds(16B), with XOR-swizzled SOURCE chunks (rule 21): LDS chunk
// (row, c) receives global chunk (row, c ^ (row&7)). Reads then XOR the same way.
DEVI void stage128(f16* lds, const f16* g, int ld, int w, int lane) {
#pragma unroll
    for (int j = 0; j < 4; ++j) {
        int q   = j * 256 + w * 64 + lane;
        int row = q >> 3;
        int c   = q & 7;
        int cs  = c ^ (row & 7);
        const f16* src = g + (size_t)row * ld + cs * 8;
        f16* dst = lds + q * 8; // byte offset q*16
        __builtin_amdgcn_global_load_lds((const __attribute__((address_space(1))) void*)src,
                                         (__attribute__((address_space(3))) void*)dst, 16, 0, 0);
    }
}

// Read an MFMA A/B fragment (8 f16) from a swizzled tile: element (row,k) lives at
// byte row*128 + ((2k) ^ ((row&7)<<4)).
DEVI f16x8 read_frag(const f16* lds, int row, int kbyte) {
    int off = row * 128 + (kbyte ^ ((row & 7) << 4));
    return *(const f16x8*)((const char*)lds + off);
}

#define MFMA(a, b, c) __builtin_amdgcn_mfma_f32_16x16x32_f16(a, b, c, 0, 0, 0)

// ---------------------------------------------------------------------------
// C[M,N] = A[M,K] * B[N,K]^T (+bias)(+rowScale), f16 inputs, f32 accumulate.
// 128x128 tile, 4 waves, BK=64. outMode: 1 = write f32 Cf, 2 = write f16 Ch
// (Ch at column offset colOff, its own ld/batch).
// ---------------------------------------------------------------------------
__global__ __launch_bounds__(256) void gemm_bt(
    const f16* __restrict__ A, const f16* __restrict__ B,
    const float* __restrict__ bias, const float* __restrict__ rowScale,
    float* __restrict__ Cf, int ldc, long batchC,
    f16* __restrict__ Ch, int ldcH, long batchCh, int colOff,
    int K, int lda, int ldb, long batchA, long batchB, int outMode)
{
    __shared__ f16 As[128 * 64];
    __shared__ f16 Bs[128 * 64];
    const int z = blockIdx.z;
    const f16* Ab = A + (size_t)z * batchA + (size_t)blockIdx.y * 128 * lda;
    const f16* Bb = B + (size_t)z * batchB + (size_t)blockIdx.x * 128 * ldb;
    const int t = threadIdx.x, w = t >> 6, lane = t & 63;
    const int r = lane & 15, h = lane >> 4;
    const int wr = w >> 1, wc = w & 1;
    f32x4v acc[4][4] = {};

#pragma unroll 1
    for (int k0 = 0; k0 < K; k0 += 64) {
        stage128(As, Ab + k0, lda, w, lane);
        stage128(Bs, Bb + k0, ldb, w, lane);
        __syncthreads();
#pragma unroll
        for (int kk = 0; kk < 2; ++kk) {
            const int kb = kk * 64 + h * 16;
            f16x8 a[4], b[4];
#pragma unroll
            for (int mi = 0; mi < 4; ++mi) a[mi] = read_frag(As, wr * 64 + mi * 16 + r, kb);
#pragma unroll
            for (int ni = 0; ni < 4; ++ni) b[ni] = read_frag(Bs, wc * 64 + ni * 16 + r, kb);
#pragma unroll
            for (int mi = 0; mi < 4; ++mi)
#pragma unroll
                for (int ni = 0; ni < 4; ++ni)
                    acc[mi][ni] = MFMA(a[mi], b[ni], acc[mi][ni]);
        }
        __syncthreads();
    }

    const int m0 = blockIdx.y * 128 + wr * 64;
    const int n0 = blockIdx.x * 128 + wc * 64;
#pragma unroll
    for (int ni = 0; ni < 4; ++ni) {
        const int col = n0 + ni * 16 + r;
        const float bv = bias ? bias[col] : 0.f;
#pragma unroll
        for (int mi = 0; mi < 4; ++mi) {
#pragma unroll
            for (int tt = 0; tt < 4; ++tt) {
                const int row = m0 + mi * 16 + h * 4 + tt;
                float v = acc[mi][ni][tt] + bv;
                if (rowScale) v *= rowScale[(size_t)z * 2048 + row];
                if (outMode & 1) Cf[(size_t)z * batchC + (size_t)row * ldc + col] = v;
                if (outMode & 2) Ch[(size_t)z * batchCh + (size_t)row * ldcH + colOff + col] = (f16)v;
            }
        }
    }
}

// ---------------------------------------------------------------------------
// f32 [B,L,D] -> f16 plain [B,L,D] and f16 transposed [B,D,L]. 64x64 tiles.
// ---------------------------------------------------------------------------
__global__ __launch_bounds__(256) void transpose_cast(
    const float* __restrict__ in, f16* __restrict__ plain, f16* __restrict__ tr)
{
    __shared__ unsigned short tile[64][72];
    const int z = blockIdx.z, l0 = blockIdx.y * 64, d0 = blockIdx.x * 64;
    const int t = threadIdx.x, r = t >> 4, c4 = (t & 15) * 4;
#pragma unroll
    for (int rep = 0; rep < 4; ++rep) {
        const int l = rep * 16 + r;
        const size_t gi = ((size_t)z * 2048 + l0 + l) * 1024 + d0 + c4;
        const f32x4v v = *(const f32x4v*)&in[gi];
        ushort4 u = make_ushort4(f2h_bits(v[0]), f2h_bits(v[1]), f2h_bits(v[2]), f2h_bits(v[3]));
        *(ushort4*)&plain[gi] = u;
        tile[c4 + 0][l] = u.x;
        tile[c4 + 1][l] = u.y;
        tile[c4 + 2][l] = u.z;
        tile[c4 + 3][l] = u.w;
    }
    __syncthreads();
#pragma unroll
    for (int rep = 0; rep < 4; ++rep) {
        const int d = rep * 16 + r;
        ushort4 u = make_ushort4(tile[d][c4 + 0], tile[d][c4 + 1], tile[d][c4 + 2], tile[d][c4 + 3]);
        *(ushort4*)&tr[((size_t)z * 1024 + d0 + d) * 2048 + l0 + c4] = u;
    }
}

__global__ void cast_w(const float* __restrict__ in, f16* __restrict__ out) {
    const int i = (blockIdx.x * 256 + threadIdx.x) * 4;
    f32x4v v = *(const f32x4v*)&in[i];
    *(ushort4*)&out[i] = make_ushort4(f2h_bits(v[0]), f2h_bits(v[1]), f2h_bits(v[2]), f2h_bits(v[3]));
}

// Wcat[o][0:1024] = Wab[o][:], Wcat[o][1024:2048] = Wba[o][:]
__global__ void cast_cat(const float* __restrict__ wab, const float* __restrict__ wba,
                         f16* __restrict__ out) {
    const int i = (blockIdx.x * 256 + threadIdx.x) * 4;
    const int row = i >> 10, col = i & 1023;
    f32x4v va = *(const f32x4v*)&wab[i];
    f32x4v vb = *(const f32x4v*)&wba[i];
    *(ushort4*)&out[(size_t)row * 2048 + col] =
        make_ushort4(f2h_bits(va[0]), f2h_bits(va[1]), f2h_bits(va[2]), f2h_bits(va[3]));
    *(ushort4*)&out[(size_t)row * 2048 + 1024 + col] =
        make_ushort4(f2h_bits(vb[0]), f2h_bits(vb[1]), f2h_bits(vb[2]), f2h_bits(vb[3]));
}

// ---------------------------------------------------------------------------
// ST is scores TRANSPOSED: ST[b][m=lb][l=la] (f32 or f16, templated).
//   row stats of ST -> cmax[m], csumInv[m]   (softmax over la, for output_a)
//   col stats of ST -> rmax[l], rsumInv[l]   (softmax over lb, for output_b)
// ---------------------------------------------------------------------------
template <typename T>
DEVI void load8_row(const T* p, int t, float* x);
template <>
DEVI void load8_row<float>(const float* p, int t, float* x) {
    const f32x4v v0 = *(const f32x4v*)&p[t * 4];
    const f32x4v v1 = *(const f32x4v*)&p[1024 + t * 4];
#pragma unroll
    for (int j = 0; j < 4; ++j) { x[j] = v0[j]; x[4 + j] = v1[j]; }
}
template <>
DEVI void load8_row<f16>(const f16* p, int t, float* x) {
    const f16x8 v = *(const f16x8*)&p[t * 8];
#pragma unroll
    for (int j = 0; j < 8; ++j) x[j] = (float)v[j];
}

template <typename T>
__global__ __launch_bounds__(256) void row_stats(const T* __restrict__ ST,
                                                 float* __restrict__ cmax,
                                                 float* __restrict__ csumInv)
{
    const size_t row = blockIdx.x;
    const T* p = ST + row * 2048;
    const int t = threadIdx.x, wid = t >> 6, lane = t & 63;
    float x[8];
    load8_row<T>(p, t, x);
    float m = x[0];
#pragma unroll
    for (int j = 1; j < 8; ++j) m = fmaxf(m, x[j]);
    for (int off = 32; off; off >>= 1) m = fmaxf(m, __shfl_xor(m, off));
    __shared__ float red[8];
    if (lane == 0) red[wid] = m;
    __syncthreads();
    m = fmaxf(fmaxf(red[0], red[1]), fmaxf(red[2], red[3]));
    float s = 0.f;
#pragma unroll
    for (int j = 0; j < 8; ++j) s += __expf(x[j] - m);
    for (int off = 32; off; off >>= 1) s += __shfl_xor(s, off);
    if (lane == 0) red[4 + wid] = s;
    __syncthreads();
    if (t == 0) {
        cmax[row] = m;
        csumInv[row] = 1.f / (red[4] + red[5] + red[6] + red[7]);
    }
}

// Column stats over m (per batch): partial (max, sumexp) over 64-row chunks.
template <typename T>
__global__ __launch_bounds__(256) void col_part(const T* __restrict__ ST,
                                                float* __restrict__ pmax,
                                                float* __restrict__ psum)
{
    const int z = blockIdx.z, mc = blockIdx.y;
    const int col = blockIdx.x * 256 + threadIdx.x;
    const T* p = ST + ((size_t)z * 2048 + (size_t)mc * 64) * 2048 + col;
    float m = -1e30f;
#pragma unroll 8
    for (int i = 0; i < 64; ++i) m = fmaxf(m, (float)p[(size_t)i * 2048]);
    float s = 0.f;
#pragma unroll 8
    for (int i = 0; i < 64; ++i) s += __expf((float)p[(size_t)i * 2048] - m);
    const size_t o = ((size_t)z * 32 + mc) * 2048 + col;
    pmax[o] = m;
    psum[o] = s;
}

__global__ void col_fin(const float* __restrict__ pmax, const float* __restrict__ psum,
                        float* __restrict__ rmax, float* __restrict__ rsumInv)
{
    const int g = blockIdx.x * 256 + threadIdx.x; // 0..16383
    const int z = g >> 11, col = g & 2047;
    const float* pm = pmax + (size_t)z * 32 * 2048 + col;
    const float* ps = psum + (size_t)z * 32 * 2048 + col;
    float m = -1e30f;
#pragma unroll
    for (int i = 0; i < 32; ++i) m = fmaxf(m, pm[(size_t)i * 2048]);
    float s = 0.f;
#pragma unroll
    for (int i = 0; i < 32; ++i) s += ps[(size_t)i * 2048] * __expf(pm[(size_t)i * 2048] - m);
    rmax[g] = m;
    rsumInv[g] = 1.f / s;
}

// ---------------------------------------------------------------------------
// Elementwise exp: PaT[m][l] = exp(ST - cmax[m]) ; PbT[m][l] = exp(ST - rmax[l])*rsumInv[l].
// Fully coalesced, no LDS. 8 elems/thread.
// ---------------------------------------------------------------------------
template <typename T>
DEVI void load8_g(const T* p, float* x);
template <>
DEVI void load8_g<float>(const float* p, float* x) {
    const f32x4v v0 = *(const f32x4v*)p;
    const f32x4v v1 = *(const f32x4v*)(p + 4);
#pragma unroll
    for (int j = 0; j < 4; ++j) { x[j] = v0[j]; x[4 + j] = v1[j]; }
}
template <>
DEVI void load8_g<f16>(const f16* p, float* x) {
    const f16x8 v = *(const f16x8*)p;
#pragma unroll
    for (int j = 0; j < 8; ++j) x[j] = (float)v[j];
}

template <typename T>
__global__ __launch_bounds__(256) void exp_p(const T* __restrict__ ST,
                                             const float* __restrict__ cmax,
                                             const float* __restrict__ rmax,
                                             const float* __restrict__ rsumInv,
                                             f16* __restrict__ Pa, f16* __restrict__ Pb)
{
    const size_t g = ((size_t)blockIdx.x * 256 + threadIdx.x) * 8;
    const int row = (int)(g >> 11);      // global m-row 0..16383
    const int z = row >> 11;
    const int l = (int)(g & 2047);
    const float cm = cmax[row];
    const float* rm = rmax + ((size_t)z << 11) + l;
    const float* ri = rsumInv + ((size_t)z << 11) + l;
    float x[8];
    load8_g<T>(ST + g, x);
    const f32x4v rm0 = *(const f32x4v*)rm, rm1 = *(const f32x4v*)(rm + 4);
    const f32x4v ri0 = *(const f32x4v*)ri, ri1 = *(const f32x4v*)(ri + 4);
    f16x8 pa, pb;
#pragma unroll
    for (int j = 0; j < 4; ++j) {
        pa[j]     = (f16)__expf(x[j] - cm);
        pa[4 + j] = (f16)__expf(x[4 + j] - cm);
        pb[j]     = (f16)(__expf(x[j] - rm0[j]) * ri0[j]);
        pb[4 + j] = (f16)(__expf(x[4 + j] - rm1[j]) * ri1[j]);
    }
    *(f16x8*)(Pa + g) = pa;
    *(f16x8*)(Pb + g) = pb;
}

// ---------------------------------------------------------------------------
extern "C" void kernel_launch(void* const* d_in, const int* in_sizes, int n_in,
                              void* d_out, int out_size, void* d_ws, size_t ws_size,
                              hipStream_t stream) {
    const float* in_a = (const float*)d_in[0];
    const float* in_b = (const float*)d_in[1];
    const float* Wa   = (const float*)d_in[2];
    const float* ba   = (const float*)d_in[3];
    const float* Wb   = (const float*)d_in[4];
    const float* bb   = (const float*)d_in[5];
    const float* Wab  = (const float*)d_in[6];
    const float* bab  = (const float*)d_in[7];
    const float* Wba  = (const float*)d_in[8];

    const size_t MB = 1u << 20;
    char* ws = (char*)d_ws;
    // ---- workspace layout (liveness overlays) ----
    // [0,32M)   aT   f16 [8,1024,2048]      (transpose_cast -> attn GEMM B)
    // [32,64M)  bT
    // [64,128M) PaT  f16 [8,2048,2048]      (exp_p -> attn GEMM A); before exp_p
    //           this region holds aB[64,96M) bB[96,128M) (transpose -> proj)
    // [128,192M)PbT; before exp_p holds maH[128,160M) mbH[160,192M) (proj -> scores)
    // [192M, +128M or +64M) ST (f32 or f16); catH [192,256M) overlays ST (attn -> final)
    // then weights + stats.
    f16*   aT  = (f16*)(ws + 0 * MB);
    f16*   bT  = (f16*)(ws + 32 * MB);
    f16*   PaT = (f16*)(ws + 64 * MB);
    f16*   PbT = (f16*)(ws + 128 * MB);
    f16*   aB  = (f16*)(ws + 64 * MB);
    f16*   bB  = (f16*)(ws + 96 * MB);
    f16*   maH = (f16*)(ws + 128 * MB);
    f16*   mbH = (f16*)(ws + 160 * MB);
    float* STf = (float*)(ws + 192 * MB);
    f16*   STh = (f16*)(ws + 192 * MB);
    f16*   catH = (f16*)(ws + 192 * MB);

    const bool useF32 = ws_size >= 334 * MB;     // f32-S needs ~333 MiB total
    char* woff = ws + 192 * MB + (useF32 ? 128 : 64) * MB;
    f16*   WaH   = (f16*)(woff + 0 * MB);
    f16*   WbH   = (f16*)(woff + 2 * MB);
    f16*   WcatH = (f16*)(woff + 4 * MB);
    float* cmaxP = (float*)(woff + 8 * MB);
    float* csumIP= (float*)(woff + 8 * MB + 64 * 1024);
    float* rmaxP = (float*)(woff + 8 * MB + 128 * 1024);
    float* rsumIP= (float*)(woff + 8 * MB + 192 * 1024);
    float* pmaxP = (float*)(woff + 9 * MB);
    float* psumP = (float*)(woff + 11 * MB);

    float* outA  = (float*)d_out;
    float* outB  = outA + 16777216;
    float* outAB = outB + 16777216;

    dim3 blk(256);
    const long LL = 2048L * 2048L, LD = 2048L * 1024L;

    transpose_cast<<<dim3(16, 32, 8), blk, 0, stream>>>(in_a, aB, aT);
    transpose_cast<<<dim3(16, 32, 8), blk, 0, stream>>>(in_b, bB, bT);
    cast_w<<<dim3(1024), blk, 0, stream>>>(Wa, WaH);
    cast_w<<<dim3(1024), blk, 0, stream>>>(Wb, WbH);
    cast_cat<<<dim3(1024), blk, 0, stream>>>(Wab, Wba, WcatH);

    // mapped_a = in_a @ Wa^T + ba (f16), mapped_b likewise
    gemm_bt<<<dim3(8, 128, 1), blk, 0, stream>>>(aB, WaH, ba, nullptr,
                                                 nullptr, 0, 0, maH, 1024, 0, 0,
                                                 1024, 1024, 1024, 0, 0, 2);
    gemm_bt<<<dim3(8, 128, 1), blk, 0, stream>>>(bB, WbH, bb, nullptr,
                                                 nullptr, 0, 0, mbH, 1024, 0, 0,
                                                 1024, 1024, 1024, 0, 0, 2);
    // ST[m][l] = scores^T = mapped_b @ mapped_a^T
    if (useF32) {
        gemm_bt<<<dim3(16, 16, 8), blk, 0, stream>>>(mbH, maH, nullptr, nullptr,
                                                     STf, 2048, LL, nullptr, 0, 0, 0,
                                                     1024, 1024, 1024, LD, LD, 1);
        row_stats<float><<<dim3(16384), blk, 0, stream>>>(STf, cmaxP, csumIP);
        col_part<float><<<dim3(8, 32, 8), blk, 0, stream>>>(STf, pmaxP, psumP);
        col_fin<<<dim3(64), blk, 0, stream>>>(pmaxP, psumP, rmaxP, rsumIP);
        exp_p<float><<<dim3(16384), blk, 0, stream>>>(STf, cmaxP, rmaxP, rsumIP, PaT, PbT);
    } else {
        gemm_bt<<<dim3(16, 16, 8), blk, 0, stream>>>(mbH, maH, nullptr, nullptr,
                                                     nullptr, 0, 0, STh, 2048, LL, 0,
                                                     1024, 1024, 1024, LD, LD, 2);
        row_stats<f16><<<dim3(16384), blk, 0, stream>>>(STh, cmaxP, csumIP);
        col_part<f16><<<dim3(8, 32, 8), blk, 0, stream>>>(STh, pmaxP, psumP);
        col_fin<<<dim3(64), blk, 0, stream>>>(pmaxP, psumP, rmaxP, rsumIP);
        exp_p<f16><<<dim3(16384), blk, 0, stream>>>(STh, cmaxP, rmaxP, rsumIP, PaT, PbT);
    }

    // output_a = csumInv * (PaT @ bT^T); output_b = PbT @ aT^T
    gemm_bt<<<dim3(8, 16, 8), blk, 0, stream>>>(PaT, bT, nullptr, csumIP,
                                                outA, 1024, LD, catH, 2048, LL, 0,
                                                2048, 2048, 2048, LL, LD, 3);
    gemm_bt<<<dim3(8, 16, 8), blk, 0, stream>>>(PbT, aT, nullptr, nullptr,
                                                outB, 1024, LD, catH, 2048, LL, 1024,
                                                2048, 2048, 2048, LL, LD, 3);

    // output_ab = cat @ Wcat^T + bab
    gemm_bt<<<dim3(8, 128, 1), blk, 0, stream>>>(catH, WcatH, bab, nullptr,
                                                 outAB, 1024, 0, nullptr, 0, 0, 0,
                                                 2048, 2048, 2048, 0, 0, 1);

    (void)in_sizes; (void)n_in; (void)out_size; (void)ws_size;
}

// Round 3
// 851.365 us; speedup vs baseline: 1.2864x; 1.1998x over previous
//
#include <hip/hip_runtime.h>

typedef _Float16 f16;
typedef __attribute__((ext_vector_type(8))) _Float16 f16x8;
typedef __attribute__((ext_vector_type(4))) float f32x4v;

#define DEVI __device__ __forceinline__

DEVI unsigned short f2h_bits(float x) {
    _Float16 h = (_Float16)x;
    return __builtin_bit_cast(unsigned short, h);
}

DEVI void wgbar() {
    asm volatile("" ::: "memory");
    __builtin_amdgcn_s_barrier();
    asm volatile("" ::: "memory");
}
DEVI void vmwait4() { asm volatile("s_waitcnt vmcnt(4)" ::: "memory"); }
DEVI void vmwait0() { asm volatile("s_waitcnt vmcnt(0)" ::: "memory"); }

// Element (row,k) of a staged tile lives at byte row*128 + ((2k) ^ ((row&7)<<4)).
DEVI f16x8 read_frag(const f16* lds, int row, int kbyte) {
    int off = row * 128 + (kbyte ^ ((row & 7) << 4));
    return *(const f16x8*)((const char*)lds + off);
}

#define MFMA(a, b, c) __builtin_amdgcn_mfma_f32_16x16x32_f16(a, b, c, 0, 0, 0)

// ---------------------------------------------------------------------------
// gemm256 staging. A-quadrant q covers rows {q*64..q*64+63} U {128+q*64..}.
// Each call: 2 global_load_lds per wave (ledger unit = 1 stage = 2 loads).
// LDS dest is wave-uniform base + lane*16B (required); source is XOR-swizzled
// per 16B chunk: global chunk (grow, c^(grow&7)) -> lds chunk (grow, c).
// ---------------------------------------------------------------------------
DEVI void stage_Aq(f16* ldsA, const f16* g, int ld, int q, int w, int lane) {
#pragma unroll
    for (int p = 0; p < 2; ++p) {
        const int qi = w * 64 + lane;                 // 0..511 per panel
        const int grow = p * 128 + q * 64 + (qi >> 3);
        const int c = qi & 7;
        const f16* src = g + (size_t)grow * ld + ((c ^ (grow & 7)) * 8);
        f16* dst = ldsA + grow * 64 + c * 8;
        __builtin_amdgcn_global_load_lds((const __attribute__((address_space(1))) void*)src,
                                         (__attribute__((address_space(3))) void*)dst, 16, 0, 0);
    }
}
// B-quadrant q covers rows {64k + q*32 .. +31} for k=0..3.
DEVI void stage_Bq(f16* ldsB, const f16* g, int ld, int q, int w, int lane) {
#pragma unroll
    for (int j = 0; j < 2; ++j) {
        const int qi = (w * 2 + j) * 64 + lane;       // 0..1023
        const int grow = (qi >> 8) * 64 + q * 32 + ((qi >> 3) & 31);
        const int c = qi & 7;
        const f16* src = g + (size_t)grow * ld + ((c ^ (grow & 7)) * 8);
        f16* dst = ldsB + grow * 64 + c * 8;
        __builtin_amdgcn_global_load_lds((const __attribute__((address_space(1))) void*)src,
                                         (__attribute__((address_space(3))) void*)dst, 16, 0, 0);
    }
}

// ---------------------------------------------------------------------------
// 256x256-tile 8-phase GEMM: C[M,N] = A[M,K]*B[N,K]^T (+bias)(+rowScale).
// 512 threads = 8 waves (2M x 4N), per-wave output 128x64, BK=64, dbuf LDS.
// Phases per iteration (2 K-tiles T0=2i buf0, T1=2i+1 buf1), quadrant order
// (0,0),(0,1),(1,1),(1,0) so each phase reloads only A or only B frags.
// Stage schedule (dest freed the phase before; tile complete before gate):
//  p1: A1.q1(T1)  p2: B1.q0(T1)  p3: A0.q0(T2)  p4: B0.q1(T2) [vmcnt(4)]
//  p5: A0.q1(T2)  p6: B0.q0(T2)  p7: A1.q0(T3)  p8: B1.q1(T3) [vmcnt(4)]
// Ledger at each gate: 6 stages x 2 loads = 12 outstanding, wait->4 newest.
// Last-iteration stages wrap via &(NT-1) (harmless, keeps ledger exact).
// ---------------------------------------------------------------------------
__global__ __launch_bounds__(512, 2) void gemm256(
    const f16* __restrict__ A, const f16* __restrict__ B,
    const float* __restrict__ bias, const float* __restrict__ rowScale,
    float* __restrict__ Cf, int ldc, long batchC,
    f16* __restrict__ Ch, int ldcH, long batchCh, int colOff,
    int K, int lda, int ldb, long batchA, long batchB, int outMode)
{
    __shared__ f16 sm[2][2][16384];   // [buf][A/B][256*64] = 128 KiB
    // XCD-aware bijective swizzle (nwg % 8 == 0 for all our grids)
    const int gx = gridDim.x, gy = gridDim.y;
    const int nwg = gx * gy * (int)gridDim.z;
    const int flat = blockIdx.x + gx * (blockIdx.y + gy * blockIdx.z);
    const int id = (flat & 7) * (nwg >> 3) + (flat >> 3);
    const int bz = id / (gx * gy);
    const int rem = id % (gx * gy);
    const int by = rem / gx, bx = rem % gx;

    const f16* Ab = A + (size_t)bz * batchA + (size_t)by * 256 * lda;
    const f16* Bb = B + (size_t)bz * batchB + (size_t)bx * 256 * ldb;
    const int t = threadIdx.x, w = t >> 6, lane = t & 63;
    const int r = lane & 15, h16 = (lane >> 4) * 16;
    const int wr = w >> 2, wc = w & 3;
    f16* A0 = sm[0][0]; f16* B0 = sm[0][1];
    f16* A1 = sm[1][0]; f16* B1 = sm[1][1];
    f32x4v acc[8][4] = {};
    f16x8 a0[4], a1[4], b0[2], b1[2];
    const int NT = K >> 6, NTm = NT - 1, NI = NT >> 1;

    // prologue: T0 -> buf0 (4 stages), T1's Aq0+Bq1 -> buf1 ("prev p7,p8")
    stage_Aq(A0, Ab, lda, 0, w, lane);
    stage_Aq(A0, Ab, lda, 1, w, lane);
    stage_Bq(B0, Bb, ldb, 0, w, lane);
    stage_Bq(B0, Bb, ldb, 1, w, lane);
    stage_Aq(A1, Ab + 64, lda, 0, w, lane);
    stage_Bq(B1, Bb + 64, ldb, 1, w, lane);
    vmwait4();   // 12 outstanding -> 4: buf0 fully landed
    wgbar();

#define LDA_(LA, QM) _Pragma("unroll") for (int mi = 0; mi < 4; ++mi) { \
        const int ar = wr * 128 + (QM) * 64 + mi * 16 + r;              \
        a0[mi] = read_frag(LA, ar, h16); a1[mi] = read_frag(LA, ar, 64 + h16); }
#define LDB_(LB, QN) _Pragma("unroll") for (int ni = 0; ni < 2; ++ni) { \
        const int br = wc * 64 + (QN) * 32 + ni * 16 + r;               \
        b0[ni] = read_frag(LB, br, h16); b1[ni] = read_frag(LB, br, 64 + h16); }
#define MM_(QM, QN) __builtin_amdgcn_s_setprio(1);                          \
    _Pragma("unroll") for (int mi = 0; mi < 4; ++mi)                        \
    _Pragma("unroll") for (int ni = 0; ni < 2; ++ni) {                      \
        acc[(QM)*4+mi][(QN)*2+ni] = MFMA(a0[mi], b0[ni], acc[(QM)*4+mi][(QN)*2+ni]); \
        acc[(QM)*4+mi][(QN)*2+ni] = MFMA(a1[mi], b1[ni], acc[(QM)*4+mi][(QN)*2+ni]); } \
    __builtin_amdgcn_s_setprio(0);

#pragma unroll 1
    for (int i = 0; i < NI; ++i) {
        const f16* At1 = Ab + ((2 * i + 1) & NTm) * 64;
        const f16* Bt1 = Bb + ((2 * i + 1) & NTm) * 64;
        const f16* At2 = Ab + ((2 * i + 2) & NTm) * 64;
        const f16* Bt2 = Bb + ((2 * i + 2) & NTm) * 64;
        const f16* At3 = Ab + ((2 * i + 3) & NTm) * 64;
        const f16* Bt3 = Bb + ((2 * i + 3) & NTm) * 64;
        // p1: Q(0,0) on buf0
        LDA_(A0, 0); LDB_(B0, 0);
        stage_Aq(A1, At1, lda, 1, w, lane);
        wgbar(); MM_(0, 0); wgbar();
        // p2: Q(0,1) — keep a, load B.q1
        LDB_(B0, 1);
        stage_Bq(B1, Bt1, ldb, 0, w, lane);
        wgbar(); MM_(0, 1); wgbar();
        // p3: Q(1,1) — keep b, load A.q1
        LDA_(A0, 1);
        stage_Aq(A0, At2, lda, 0, w, lane);
        wgbar(); MM_(1, 1); wgbar();
        // p4: Q(1,0) — keep a, load B.q0; gate buf1
        LDB_(B0, 0);
        stage_Bq(B0, Bt2, ldb, 1, w, lane);
        wgbar(); MM_(1, 0); vmwait4(); wgbar();
        // p5: Q(0,0) on buf1
        LDA_(A1, 0); LDB_(B1, 0);
        stage_Aq(A0, At2, lda, 1, w, lane);
        wgbar(); MM_(0, 0); wgbar();
        // p6
        LDB_(B1, 1);
        stage_Bq(B0, Bt2, ldb, 0, w, lane);
        wgbar(); MM_(0, 1); wgbar();
        // p7
        LDA_(A1, 1);
        stage_Aq(A1, At3, lda, 0, w, lane);
        wgbar(); MM_(1, 1); wgbar();
        // p8: gate buf0
        LDB_(B1, 0);
        stage_Bq(B1, Bt3, ldb, 1, w, lane);
        wgbar(); MM_(1, 0); vmwait4(); wgbar();
    }
    vmwait0();   // drain dangling global_load_lds before epilogue/endpgm

    const int m0 = by * 256 + wr * 128;
    const int n0 = bx * 256 + wc * 64;
    const int h4 = (lane >> 4) * 4;
#pragma unroll
    for (int ni2 = 0; ni2 < 4; ++ni2) {
        const int col = n0 + ni2 * 16 + r;
        const float bv = bias ? bias[col] : 0.f;
#pragma unroll
        for (int mi2 = 0; mi2 < 8; ++mi2) {
#pragma unroll
            for (int tt = 0; tt < 4; ++tt) {
                const int row = m0 + mi2 * 16 + h4 + tt;
                float v = acc[mi2][ni2][tt] + bv;
                if (rowScale) v *= rowScale[(size_t)bz * 2048 + row];
                if (outMode & 1) Cf[(size_t)bz * batchC + (size_t)row * ldc + col] = v;
                if (outMode & 2) Ch[(size_t)bz * batchCh + (size_t)row * ldcH + colOff + col] = (f16)v;
            }
        }
    }
}

// ---------------------------------------------------------------------------
// f32 [B,L,D] -> f16 plain [B,L,D] and f16 transposed [B,D,L]. 64x64 tiles.
// ---------------------------------------------------------------------------
__global__ __launch_bounds__(256) void transpose_cast(
    const float* __restrict__ in, f16* __restrict__ plain, f16* __restrict__ tr)
{
    __shared__ unsigned short tile[64][72];
    const int z = blockIdx.z, l0 = blockIdx.y * 64, d0 = blockIdx.x * 64;
    const int t = threadIdx.x, r = t >> 4, c4 = (t & 15) * 4;
#pragma unroll
    for (int rep = 0; rep < 4; ++rep) {
        const int l = rep * 16 + r;
        const size_t gi = ((size_t)z * 2048 + l0 + l) * 1024 + d0 + c4;
        const f32x4v v = *(const f32x4v*)&in[gi];
        ushort4 u = make_ushort4(f2h_bits(v[0]), f2h_bits(v[1]), f2h_bits(v[2]), f2h_bits(v[3]));
        *(ushort4*)&plain[gi] = u;
        tile[c4 + 0][l] = u.x;
        tile[c4 + 1][l] = u.y;
        tile[c4 + 2][l] = u.z;
        tile[c4 + 3][l] = u.w;
    }
    __syncthreads();
#pragma unroll
    for (int rep = 0; rep < 4; ++rep) {
        const int d = rep * 16 + r;
        ushort4 u = make_ushort4(tile[d][c4 + 0], tile[d][c4 + 1], tile[d][c4 + 2], tile[d][c4 + 3]);
        *(ushort4*)&tr[((size_t)z * 1024 + d0 + d) * 2048 + l0 + c4] = u;
    }
}

__global__ void cast_w(const float* __restrict__ in, f16* __restrict__ out) {
    const int i = (blockIdx.x * 256 + threadIdx.x) * 4;
    f32x4v v = *(const f32x4v*)&in[i];
    *(ushort4*)&out[i] = make_ushort4(f2h_bits(v[0]), f2h_bits(v[1]), f2h_bits(v[2]), f2h_bits(v[3]));
}

__global__ void cast_cat(const float* __restrict__ wab, const float* __restrict__ wba,
                         f16* __restrict__ out) {
    const int i = (blockIdx.x * 256 + threadIdx.x) * 4;
    const int row = i >> 10, col = i & 1023;
    f32x4v va = *(const f32x4v*)&wab[i];
    f32x4v vb = *(const f32x4v*)&wba[i];
    *(ushort4*)&out[(size_t)row * 2048 + col] =
        make_ushort4(f2h_bits(va[0]), f2h_bits(va[1]), f2h_bits(va[2]), f2h_bits(va[3]));
    *(ushort4*)&out[(size_t)row * 2048 + 1024 + col] =
        make_ushort4(f2h_bits(vb[0]), f2h_bits(vb[1]), f2h_bits(vb[2]), f2h_bits(vb[3]));
}

// ---------------------------------------------------------------------------
// Stats on ST (scores transposed): row stats -> cmax/csumInv (softmax over la),
// col stats -> rmax/rsumInv (softmax over lb).
// ---------------------------------------------------------------------------
template <typename T>
DEVI void load8_row(const T* p, int t, float* x);
template <>
DEVI void load8_row<float>(const float* p, int t, float* x) {
    const f32x4v v0 = *(const f32x4v*)&p[t * 4];
    const f32x4v v1 = *(const f32x4v*)&p[1024 + t * 4];
#pragma unroll
    for (int j = 0; j < 4; ++j) { x[j] = v0[j]; x[4 + j] = v1[j]; }
}
template <>
DEVI void load8_row<f16>(const f16* p, int t, float* x) {
    const f16x8 v = *(const f16x8*)&p[t * 8];
#pragma unroll
    for (int j = 0; j < 8; ++j) x[j] = (float)v[j];
}

template <typename T>
__global__ __launch_bounds__(256) void row_stats(const T* __restrict__ ST,
                                                 float* __restrict__ cmax,
                                                 float* __restrict__ csumInv)
{
    const size_t row = blockIdx.x;
    const T* p = ST + row * 2048;
    const int t = threadIdx.x, wid = t >> 6, lane = t & 63;
    float x[8];
    load8_row<T>(p, t, x);
    float m = x[0];
#pragma unroll
    for (int j = 1; j < 8; ++j) m = fmaxf(m, x[j]);
    for (int off = 32; off; off >>= 1) m = fmaxf(m, __shfl_xor(m, off));
    __shared__ float red[8];
    if (lane == 0) red[wid] = m;
    __syncthreads();
    m = fmaxf(fmaxf(red[0], red[1]), fmaxf(red[2], red[3]));
    float s = 0.f;
#pragma unroll
    for (int j = 0; j < 8; ++j) s += __expf(x[j] - m);
    for (int off = 32; off; off >>= 1) s += __shfl_xor(s, off);
    if (lane == 0) red[4 + wid] = s;
    __syncthreads();
    if (t == 0) {
        cmax[row] = m;
        csumInv[row] = 1.f / (red[4] + red[5] + red[6] + red[7]);
    }
}

template <typename T>
__global__ __launch_bounds__(256) void col_part(const T* __restrict__ ST,
                                                float* __restrict__ pmax,
                                                float* __restrict__ psum)
{
    const int z = blockIdx.z, mc = blockIdx.y;
    const int col = blockIdx.x * 256 + threadIdx.x;
    const T* p = ST + ((size_t)z * 2048 + (size_t)mc * 64) * 2048 + col;
    float m = -1e30f;
#pragma unroll 8
    for (int i = 0; i < 64; ++i) m = fmaxf(m, (float)p[(size_t)i * 2048]);
    float s = 0.f;
#pragma unroll 8
    for (int i = 0; i < 64; ++i) s += __expf((float)p[(size_t)i * 2048] - m);
    const size_t o = ((size_t)z * 32 + mc) * 2048 + col;
    pmax[o] = m;
    psum[o] = s;
}

__global__ void col_fin(const float* __restrict__ pmax, const float* __restrict__ psum,
                        float* __restrict__ rmax, float* __restrict__ rsumInv)
{
    const int g = blockIdx.x * 256 + threadIdx.x;
    const int z = g >> 11, col = g & 2047;
    const float* pm = pmax + (size_t)z * 32 * 2048 + col;
    const float* ps = psum + (size_t)z * 32 * 2048 + col;
    float m = -1e30f;
#pragma unroll
    for (int i = 0; i < 32; ++i) m = fmaxf(m, pm[(size_t)i * 2048]);
    float s = 0.f;
#pragma unroll
    for (int i = 0; i < 32; ++i) s += ps[(size_t)i * 2048] * __expf(pm[(size_t)i * 2048] - m);
    rmax[g] = m;
    rsumInv[g] = 1.f / s;
}

// ---------------------------------------------------------------------------
// Elementwise exp: PaT = exp(ST - cmax[m]); PbT = exp(ST - rmax[l])*rsumInv[l].
// ---------------------------------------------------------------------------
template <typename T>
DEVI void load8_g(const T* p, float* x);
template <>
DEVI void load8_g<float>(const float* p, float* x) {
    const f32x4v v0 = *(const f32x4v*)p;
    const f32x4v v1 = *(const f32x4v*)(p + 4);
#pragma unroll
    for (int j = 0; j < 4; ++j) { x[j] = v0[j]; x[4 + j] = v1[j]; }
}
template <>
DEVI void load8_g<f16>(const f16* p, float* x) {
    const f16x8 v = *(const f16x8*)p;
#pragma unroll
    for (int j = 0; j < 8; ++j) x[j] = (float)v[j];
}

template <typename T>
__global__ __launch_bounds__(256) void exp_p(const T* __restrict__ ST,
                                             const float* __restrict__ cmax,
                                             const float* __restrict__ rmax,
                                             const float* __restrict__ rsumInv,
                                             f16* __restrict__ Pa, f16* __restrict__ Pb)
{
    const size_t g = ((size_t)blockIdx.x * 256 + threadIdx.x) * 8;
    const int row = (int)(g >> 11);
    const int z = row >> 11;
    const int l = (int)(g & 2047);
    const float cm = cmax[row];
    const float* rm = rmax + ((size_t)z << 11) + l;
    const float* ri = rsumInv + ((size_t)z << 11) + l;
    float x[8];
    load8_g<T>(ST + g, x);
    const f32x4v rm0 = *(const f32x4v*)rm, rm1 = *(const f32x4v*)(rm + 4);
    const f32x4v ri0 = *(const f32x4v*)ri, ri1 = *(const f32x4v*)(ri + 4);
    f16x8 pa, pb;
#pragma unroll
    for (int j = 0; j < 4; ++j) {
        pa[j]     = (f16)__expf(x[j] - cm);
        pa[4 + j] = (f16)__expf(x[4 + j] - cm);
        pb[j]     = (f16)(__expf(x[j] - rm0[j]) * ri0[j]);
        pb[4 + j] = (f16)(__expf(x[4 + j] - rm1[j]) * ri1[j]);
    }
    *(f16x8*)(Pa + g) = pa;
    *(f16x8*)(Pb + g) = pb;
}

// ---------------------------------------------------------------------------
extern "C" void kernel_launch(void* const* d_in, const int* in_sizes, int n_in,
                              void* d_out, int out_size, void* d_ws, size_t ws_size,
                              hipStream_t stream) {
    const float* in_a = (const float*)d_in[0];
    const float* in_b = (const float*)d_in[1];
    const float* Wa   = (const float*)d_in[2];
    const float* ba   = (const float*)d_in[3];
    const float* Wb   = (const float*)d_in[4];
    const float* bb   = (const float*)d_in[5];
    const float* Wab  = (const float*)d_in[6];
    const float* bab  = (const float*)d_in[7];
    const float* Wba  = (const float*)d_in[8];

    const size_t MB = 1u << 20;
    char* ws = (char*)d_ws;
    f16*   aT  = (f16*)(ws + 0 * MB);
    f16*   bT  = (f16*)(ws + 32 * MB);
    f16*   PaT = (f16*)(ws + 64 * MB);
    f16*   PbT = (f16*)(ws + 128 * MB);
    f16*   aB  = (f16*)(ws + 64 * MB);
    f16*   bB  = (f16*)(ws + 96 * MB);
    f16*   maH = (f16*)(ws + 128 * MB);
    f16*   mbH = (f16*)(ws + 160 * MB);
    float* STf = (float*)(ws + 192 * MB);
    f16*   STh = (f16*)(ws + 192 * MB);
    f16*   catH = (f16*)(ws + 192 * MB);

    const bool useF32 = ws_size >= 334 * MB;
    char* woff = ws + 192 * MB + (useF32 ? 128 : 64) * MB;
    f16*   WaH   = (f16*)(woff + 0 * MB);
    f16*   WbH   = (f16*)(woff + 2 * MB);
    f16*   WcatH = (f16*)(woff + 4 * MB);
    float* cmaxP = (float*)(woff + 8 * MB);
    float* csumIP= (float*)(woff + 8 * MB + 64 * 1024);
    float* rmaxP = (float*)(woff + 8 * MB + 128 * 1024);
    float* rsumIP= (float*)(woff + 8 * MB + 192 * 1024);
    float* pmaxP = (float*)(woff + 9 * MB);
    float* psumP = (float*)(woff + 11 * MB);

    float* outA  = (float*)d_out;
    float* outB  = outA + 16777216;
    float* outAB = outB + 16777216;

    dim3 blk(256), blk512(512);
    const long LL = 2048L * 2048L, LD = 2048L * 1024L;

    transpose_cast<<<dim3(16, 32, 8), blk, 0, stream>>>(in_a, aB, aT);
    transpose_cast<<<dim3(16, 32, 8), blk, 0, stream>>>(in_b, bB, bT);
    cast_w<<<dim3(1024), blk, 0, stream>>>(Wa, WaH);
    cast_w<<<dim3(1024), blk, 0, stream>>>(Wb, WbH);
    cast_cat<<<dim3(1024), blk, 0, stream>>>(Wab, Wba, WcatH);

    // mapped_a = in_a @ Wa^T + ba (f16), mapped_b likewise  (M=16384,N=1024,K=1024)
    gemm256<<<dim3(4, 64, 1), blk512, 0, stream>>>(aB, WaH, ba, nullptr,
                                                   nullptr, 0, 0, maH, 1024, 0, 0,
                                                   1024, 1024, 1024, 0, 0, 2);
    gemm256<<<dim3(4, 64, 1), blk512, 0, stream>>>(bB, WbH, bb, nullptr,
                                                   nullptr, 0, 0, mbH, 1024, 0, 0,
                                                   1024, 1024, 1024, 0, 0, 2);
    // ST[m][l] = scores^T = mapped_b @ mapped_a^T  (M=N=2048,K=1024, batch 8)
    if (useF32) {
        gemm256<<<dim3(8, 8, 8), blk512, 0, stream>>>(mbH, maH, nullptr, nullptr,
                                                      STf, 2048, LL, nullptr, 0, 0, 0,
                                                      1024, 1024, 1024, LD, LD, 1);
        row_stats<float><<<dim3(16384), blk, 0, stream>>>(STf, cmaxP, csumIP);
        col_part<float><<<dim3(8, 32, 8), blk, 0, stream>>>(STf, pmaxP, psumP);
        col_fin<<<dim3(64), blk, 0, stream>>>(pmaxP, psumP, rmaxP, rsumIP);
        exp_p<float><<<dim3(16384), blk, 0, stream>>>(STf, cmaxP, rmaxP, rsumIP, PaT, PbT);
    } else {
        gemm256<<<dim3(8, 8, 8), blk512, 0, stream>>>(mbH, maH, nullptr, nullptr,
                                                      nullptr, 0, 0, STh, 2048, LL, 0,
                                                      1024, 1024, 1024, LD, LD, 2);
        row_stats<f16><<<dim3(16384), blk, 0, stream>>>(STh, cmaxP, csumIP);
        col_part<f16><<<dim3(8, 32, 8), blk, 0, stream>>>(STh, pmaxP, psumP);
        col_fin<<<dim3(64), blk, 0, stream>>>(pmaxP, psumP, rmaxP, rsumIP);
        exp_p<f16><<<dim3(16384), blk, 0, stream>>>(STh, cmaxP, rmaxP, rsumIP, PaT, PbT);
    }

    // output_a = csumInv * (PaT @ bT^T); output_b = PbT @ aT^T  (M=2048,N=1024,K=2048,b8)
    gemm256<<<dim3(4, 8, 8), blk512, 0, stream>>>(PaT, bT, nullptr, csumIP,
                                                  outA, 1024, LD, catH, 2048, LL, 0,
                                                  2048, 2048, 2048, LL, LD, 3);
    gemm256<<<dim3(4, 8, 8), blk512, 0, stream>>>(PbT, aT, nullptr, nullptr,
                                                  outB, 1024, LD, catH, 2048, LL, 1024,
                                                  2048, 2048, 2048, LL, LD, 3);

    // output_ab = cat @ Wcat^T + bab  (M=16384,N=1024,K=2048)
    gemm256<<<dim3(4, 64, 1), blk512, 0, stream>>>(catH, WcatH, bab, nullptr,
                                                   outAB, 1024, 0, nullptr, 0, 0, 0,
                                                   2048, 2048, 2048, 0, 0, 1);

    (void)in_sizes; (void)n_in; (void)out_size; (void)ws_size;
}